// Round 16
// baseline (1395.746 us; speedup 1.0000x reference)
//
#include <hip/hip_runtime.h>
#include <stdint.h>
#include <stddef.h>

#define NROWS 65536
#define BM 256
#define NBLK (NROWS / BM)   // 256 blocks x 512 threads, 1 block/CU... (512 blocks total /BM=256 -> 256)

typedef __attribute__((ext_vector_type(8))) short bf16x8;
typedef __attribute__((ext_vector_type(16))) float f32x16;

// per-step constants, host-precomputed with the exact f32 op sequence of the reference
struct Consts {
  unsigned k0[32]; unsigned k1[32];
  float s1d[32];    // sqrt(1 - alpha_bar[t])
  float sqa[32];    // sqrt(alpha[t])
  float sqb[32];    // sqrt(beta[t])
  float inva[32];   // 1 / sqrt(alpha_bar[t])
};

// ---------- helpers ----------
__device__ __forceinline__ unsigned short f2bf(float f) {
  unsigned u = __float_as_uint(f);
  u += 0x7fffu + ((u >> 16) & 1u);          // RNE to bf16
  return (unsigned short)(u >> 16);
}

__device__ __forceinline__ unsigned cvtpk(float lo, float hi) {
  unsigned r;
  asm("v_cvt_pk_bf16_f32 %0, %1, %2" : "=v"(r) : "v"(lo), "v"(hi));
  return r;
}

__device__ __forceinline__ float silu(float v) {
  return v * __builtin_amdgcn_rcpf(1.0f + __expf(-v));
}

__device__ __forceinline__ void gload_lds16(const void* g, void* l) {
  __builtin_amdgcn_global_load_lds(
      (const __attribute__((address_space(1))) unsigned int*)g,
      (__attribute__((address_space(3))) unsigned int*)l, 16, 0, 0);
}

// Exact JAX noise, threefry_partitionable (verified round 2).
__device__ __forceinline__ float noise_normal(unsigned k0, unsigned k1, unsigned idx) {
  unsigned x0 = 0u, x1 = idx;
  unsigned ks2 = k0 ^ k1 ^ 0x1BD11BDAu;
  x0 += k0; x1 += k1;
#define TFR(r) { x0 += x1; x1 = (x1 << r) | (x1 >> (32 - r)); x1 ^= x0; }
  TFR(13) TFR(15) TFR(26) TFR(6)
  x0 += k1;  x1 += ks2 + 1u;
  TFR(17) TFR(29) TFR(16) TFR(24)
  x0 += ks2; x1 += k0 + 2u;
  TFR(13) TFR(15) TFR(26) TFR(6)
  x0 += k0;  x1 += k1 + 3u;
  TFR(17) TFR(29) TFR(16) TFR(24)
  x0 += k1;  x1 += ks2 + 4u;
  TFR(13) TFR(15) TFR(26) TFR(6)
  x0 += ks2; x1 += k0 + 5u;
#undef TFR
  unsigned bits = x0 ^ x1;
  float f = __uint_as_float((bits >> 9) | 0x3f800000u) - 1.0f;
  const float mn = -0.99999994f;
  float u = f * 2.0f + mn;
  u = fmaxf(mn, u);
  float w = -__logf(fmaf(-u, u, 1.0f));     // == -log1p(-u*u) to ~1e-6 rel
  float p;
  if (w < 5.0f) {
    w -= 2.5f;
    p = 2.81022636e-08f;
    p = fmaf(p, w, 3.43273939e-07f);
    p = fmaf(p, w, -3.5233877e-06f);
    p = fmaf(p, w, -4.39150654e-06f);
    p = fmaf(p, w, 0.00021858087f);
    p = fmaf(p, w, -0.00125372503f);
    p = fmaf(p, w, -0.00417768164f);
    p = fmaf(p, w, 0.246640727f);
    p = fmaf(p, w, 1.50140941f);
  } else {
    w = sqrtf(w) - 3.0f;
    p = -0.000200214257f;
    p = fmaf(p, w, 0.000100950558f);
    p = fmaf(p, w, 0.00134934322f);
    p = fmaf(p, w, -0.00367342844f);
    p = fmaf(p, w, 0.00573950773f);
    p = fmaf(p, w, -0.0076224613f);
    p = fmaf(p, w, 0.00943887047f);
    p = fmaf(p, w, 1.00167406f);
    p = fmaf(p, w, 2.83297682f);
  }
  return 1.41421356f * (p * u);
}

// ---------- init kernels ----------
// wbuf: 480 frags x 1 KB (32x32x16 A-frags, bf16).
//   [0,32):    w1x  [p(4)][ctl(2)][kt(4)]   W1 rows 0..63
//   [32,160):  W2   [cp(4)][ctl(2)][kt(16)]
//   [160,288): W3   [cp(4)][ctl(2)][kt(16)]
//   [288,320): W4   [ctl(2)][kt(16)]
//   [320,480): w1c  [cp(4)][ctl(2)][kt(16)] W1 rows 96..351 (used only by pcond_k)
// frag elem (lane l, e): A[n = 32ct + (l&31)][k = 16kt + (l>>5)*8 + e] = W[k][n]
__global__ void pack_w_k(const float* __restrict__ W1, const float* __restrict__ W2,
                         const float* __restrict__ W3, const float* __restrict__ W4,
                         unsigned short* __restrict__ wbuf) {
  int o = blockIdx.x * 256 + threadIdx.x;     // 960 blocks -> 245760 ushorts
  int f = o >> 9, q = o & 511, l = q >> 3, e = q & 7;
  int l31 = l & 31, kex = (l >> 5) * 8 + e;
  float v;
  if (f < 32) {
    int p = f >> 3, ctl = (f >> 2) & 1, kt = f & 3;
    v = W1[(16 * kt + kex) * 256 + 32 * (2 * p + ctl) + l31];
  } else if (f < 160) {
    int g = f - 32; int cp = g >> 5, ctl = (g >> 4) & 1, kt = g & 15;
    v = W2[(16 * kt + kex) * 256 + 32 * (2 * cp + ctl) + l31];
  } else if (f < 288) {
    int g = f - 160; int cp = g >> 5, ctl = (g >> 4) & 1, kt = g & 15;
    v = W3[(16 * kt + kex) * 256 + 32 * (2 * cp + ctl) + l31];
  } else if (f < 320) {
    int g = f - 288; int ctl = g >> 4, kt = g & 15;
    v = W4[(16 * kt + kex) * 64 + 32 * ctl + l31];
  } else {
    int g = f - 320; int cp = g >> 5, ctl = (g >> 4) & 1, kt = g & 15;
    v = W1[(96 + 16 * kt + kex) * 256 + 32 * (2 * cp + ctl) + l31];
  }
  wbuf[o] = f2bf(v);
}

// b1eff[t][n] = b1[n] + sum_j temb(t)[j] * W1[64+j][n], stored SWIZZLED to D-reg order:
// pos = ct*32 + kh*16 + r, where n = 32ct + (r&3) + 8*(r>>2) + 4*kh
__global__ void b1eff_k(const float* __restrict__ W1, const float* __restrict__ b1,
                        float* __restrict__ b1eff) {
  int t = blockIdx.x, n = threadIdx.x;
  float acc = b1[n];
#pragma unroll
  for (int j = 0; j < 16; ++j) {
    float arg = (float)t * expf((float)j * (6.907755278982137f / 15.0f));
    acc += sinf(arg) * W1[(64 + j) * 256 + n] + cosf(arg) * W1[(80 + j) * 256 + n];
  }
  int sw = ((n >> 5) << 5) + (((n >> 2) & 1) << 4) + (n & 3) + (((n >> 3) & 3) << 2);
  b1eff[t * 256 + sw] = acc;
}

#define MF32(W, B, C) __builtin_amdgcn_mfma_f32_32x32x16_bf16((W), (B), (C), 0, 0, 0)

// ---------- P = cond @ W1c, once, stored bf16 in D-reg order ----------
// layout: P[slot = 2*ct + kh][row][16 bf16]
__global__ __launch_bounds__(256) void pcond_k(const float* __restrict__ cond,
                                               const unsigned short* __restrict__ wbuf,
                                               unsigned short* __restrict__ P) {
  const int tid = threadIdx.x;
  const int wave = tid >> 6, lane = tid & 63;
  const int l31 = lane & 31, kh = lane >> 5;
  const int row = blockIdx.x * 128 + wave * 32 + l31;

  bf16x8 cf[16];
#pragma unroll
  for (int kt = 0; kt < 16; ++kt) {
    const float* p = cond + (size_t)row * 256 + 16 * kt + 8 * kh;
    float4 a = *(const float4*)p;
    float4 b = *(const float4*)(p + 4);
    union { bf16x8 f; unsigned u[4]; } cu;
    cu.u[0] = cvtpk(a.x, a.y); cu.u[1] = cvtpk(a.z, a.w);
    cu.u[2] = cvtpk(b.x, b.y); cu.u[3] = cvtpk(b.z, b.w);
    cf[kt] = cu.f;
  }

#define PSTORE(AV, CT) do { \
  uint4 u0_, u1_; \
  u0_.x = cvtpk(AV[0], AV[1]);   u0_.y = cvtpk(AV[2], AV[3]); \
  u0_.z = cvtpk(AV[4], AV[5]);   u0_.w = cvtpk(AV[6], AV[7]); \
  u1_.x = cvtpk(AV[8], AV[9]);   u1_.y = cvtpk(AV[10], AV[11]); \
  u1_.z = cvtpk(AV[12], AV[13]); u1_.w = cvtpk(AV[14], AV[15]); \
  uint4* pp_ = (uint4*)(P + ((size_t)((CT) * 2 + kh) * 65536 + (size_t)row) * 16); \
  pp_[0] = u0_; pp_[1] = u1_; \
} while (0)

#pragma unroll
  for (int cp = 0; cp < 4; ++cp) {
    f32x16 a0, a1;
#pragma unroll
    for (int z = 0; z < 16; ++z) { a0[z] = 0.0f; a1[z] = 0.0f; }
#pragma unroll
    for (int kt = 0; kt < 16; ++kt) {
      bf16x8 w0 = *(const bf16x8*)(wbuf + (size_t)(320 + cp * 32 + kt) * 512 + lane * 8);
      bf16x8 w1 = *(const bf16x8*)(wbuf + (size_t)(320 + cp * 32 + 16 + kt) * 512 + lane * 8);
      a0 = MF32(w0, cf[kt], a0);
      a1 = MF32(w1, cf[kt], a1);
    }
    PSTORE(a0, 2 * cp);
    PSTORE(a1, 2 * cp + 1);
  }
#undef PSTORE
}

// ---------- weight-chunk staging: 10 chunks/step x 32 KB, double-buffered ----------
// LDS bytes: [0,65536) weight dbuf (2x32KB) | [65536,131072) xlds | [131072,134400) biasF
__device__ __forceinline__ void issue_chunk(const unsigned short* __restrict__ wsW,
                                            const float* __restrict__ b1eff,
                                            unsigned short* smem, int k, int tid) {
  if (k >= 320) return;
  int c = k % 10;
  unsigned short* dst = smem + (k & 1) * 16384;
  const unsigned short* src = wsW + c * 16384;
#pragma unroll
  for (int i = 0; i < 4; ++i) {
    int off = (i * 512 + tid) * 8;
    gload_lds16(src + off, dst + off);
  }
  if (c == 9 && tid < 64) {                    // prefetch next step's b1eff
    int tn = 30 - k / 10;
    if (tn >= 0) gload_lds16(b1eff + tn * 256 + tid * 4, (float*)(smem + 65536) + tid * 4);
  }
}

// build 2 B-frags (32 cols -> k-tiles 2ct,2ct+1) from 16 f32 in D-reg order (r6-verified)
#define FRAGBUILD(vv, D0, D1) do { \
  unsigned c0_ = cvtpk(vv[0], vv[1]),  c2_ = cvtpk(vv[2], vv[3]); \
  unsigned c1_ = cvtpk(vv[4], vv[5]),  c3_ = cvtpk(vv[6], vv[7]); \
  asm volatile("v_permlane32_swap_b32 %0, %1" : "+v"(c0_), "+v"(c1_)); \
  asm volatile("v_permlane32_swap_b32 %0, %1" : "+v"(c2_), "+v"(c3_)); \
  union { bf16x8 f; unsigned u[4]; } F0_; \
  F0_.u[0] = c0_; F0_.u[1] = c2_; F0_.u[2] = c1_; F0_.u[3] = c3_; (D0) = F0_.f; \
  unsigned d0_ = cvtpk(vv[8], vv[9]),   d2_ = cvtpk(vv[10], vv[11]); \
  unsigned d1_ = cvtpk(vv[12], vv[13]), d3_ = cvtpk(vv[14], vv[15]); \
  asm volatile("v_permlane32_swap_b32 %0, %1" : "+v"(d0_), "+v"(d1_)); \
  asm volatile("v_permlane32_swap_b32 %0, %1" : "+v"(d2_), "+v"(d3_)); \
  union { bf16x8 f; unsigned u[4]; } F1_; \
  F1_.u[0] = d0_; F1_.u[1] = d2_; F1_.u[2] = d1_; F1_.u[3] = d3_; (D1) = F1_.f; \
} while (0)

// bias-add + silu + repack to B-frags
#define ACTF(AV, BOFF, CT, D0, D1) do { \
  const float* bp_ = biasF + (BOFF) + (CT) * 32 + kh * 16; \
  float4 b0_ = *(const float4*)bp_; \
  float4 b1_ = *(const float4*)(bp_ + 4); \
  float4 b2_ = *(const float4*)(bp_ + 8); \
  float4 b3_ = *(const float4*)(bp_ + 12); \
  float vv[16]; \
  vv[0]=AV[0]+b0_.x; vv[1]=AV[1]+b0_.y; vv[2]=AV[2]+b0_.z; vv[3]=AV[3]+b0_.w; \
  vv[4]=AV[4]+b1_.x; vv[5]=AV[5]+b1_.y; vv[6]=AV[6]+b1_.z; vv[7]=AV[7]+b1_.w; \
  vv[8]=AV[8]+b2_.x; vv[9]=AV[9]+b2_.y; vv[10]=AV[10]+b2_.z; vv[11]=AV[11]+b2_.w; \
  vv[12]=AV[12]+b3_.x; vv[13]=AV[13]+b3_.y; vv[14]=AV[14]+b3_.z; vv[15]=AV[15]+b3_.w; \
  _Pragma("unroll") for (int r_ = 0; r_ < 16; ++r_) vv[r_] = silu(vv[r_]); \
  FRAGBUILD(vv, D0, D1); \
} while (0)

// silu-only (bias already in acc) + repack
#define ACTF0(AV, D0, D1) do { \
  float vv[16]; \
  _Pragma("unroll") for (int r_ = 0; r_ < 16; ++r_) vv[r_] = silu(AV[r_]); \
  FRAGBUILD(vv, D0, D1); \
} while (0)

// acc init = P(bf16, D-order) + b1eff_t (LDS, D-order)
#define PDEC(ACC, PA, PB, CT) do { \
  const float* bb_ = biasF + (CT) * 32 + kh * 16; \
  float4 b0_ = *(const float4*)bb_; \
  float4 b1_ = *(const float4*)(bb_ + 4); \
  float4 b2_ = *(const float4*)(bb_ + 8); \
  float4 b3_ = *(const float4*)(bb_ + 12); \
  float ba_[16] = {b0_.x,b0_.y,b0_.z,b0_.w, b1_.x,b1_.y,b1_.z,b1_.w, \
                   b2_.x,b2_.y,b2_.z,b2_.w, b3_.x,b3_.y,b3_.z,b3_.w}; \
  unsigned uu_[8] = {PA.x, PA.y, PA.z, PA.w, PB.x, PB.y, PB.z, PB.w}; \
  _Pragma("unroll") for (int w_ = 0; w_ < 8; ++w_) { \
    ACC[2 * w_]     = __uint_as_float(uu_[w_] << 16)          + ba_[2 * w_]; \
    ACC[2 * w_ + 1] = __uint_as_float(uu_[w_] & 0xffff0000u)  + ba_[2 * w_ + 1]; } \
} while (0)

#define NEXTCHUNK() do { __syncthreads(); ++ck; \
  bufp = smem + (ck & 1) * 16384; \
  issue_chunk(wsW, b1eff, smem, ck + 1, tid); } while (0)

#define ZER16(A) { _Pragma("unroll") for (int z_ = 0; z_ < 16; ++z_) (A)[z_] = 0.0f; }

// ---------- main persistent kernel ----------
__global__ __launch_bounds__(512, 1) void diff_main(
    const float* __restrict__ x_init,
    const float* __restrict__ b2g, const float* __restrict__ b3g, const float* __restrict__ b4g,
    const unsigned short* __restrict__ wsW, const float* __restrict__ b1eff,
    const unsigned short* __restrict__ Pglob,
    float* __restrict__ out, Consts C) {
  extern __shared__ unsigned short smem[];
  float* xlds  = (float*)(smem + 32768);       // byte 65536: 64 KB x-master [wave][q][lane][4]
  float* biasF = (float*)(smem + 65536);       // byte 131072: b1eff_t[256] b2[256] b3[256] b4[64]

  const int tid = threadIdx.x;
  const int wave = tid >> 6, lane = tid & 63;
  const int l31 = lane & 31, kh = lane >> 5;
  const int lane8 = lane * 8;
  // T1 XCD swizzle: 256 blocks, 8 XCDs, bijective (256 = 8*32):
  // each XCD gets a contiguous 32-block (8192-row) slice -> its 4MB P slice is L2-resident.
  const int bid = blockIdx.x;
  const int sbid = ((bid & 7) << 5) | (bid >> 3);
  const int row = sbid * BM + wave * 32 + l31;

  // stage b2/b3/b4 -> LDS, swizzled to D-reg order
  for (int i = tid; i < 576; i += 512) {
    float v; int n, base;
    if (i < 256)      { v = b2g[i];       n = i;       base = 256; }
    else if (i < 512) { v = b3g[i - 256]; n = i - 256; base = 512; }
    else              { v = b4g[i - 512]; n = i - 512; base = 768; }
    int sw = ((n >> 5) << 5) + (((n >> 2) & 1) << 4) + (n & 3) + (((n >> 3) & 3) << 2);
    biasF[base + sw] = v;
  }
  // stage b1eff[31]
  if (tid < 64) gload_lds16(b1eff + 31 * 256 + tid * 4, biasF + tid * 4);

  // x master -> LDS (frags rebuilt from LDS at each step's c0)
#pragma unroll
  for (int ct4 = 0; ct4 < 2; ++ct4) {
#pragma unroll
    for (int g = 0; g < 4; ++g) {
      float4 xv = *(const float4*)(x_init + (size_t)row * 64 + 32 * ct4 + 8 * g + 4 * kh);
      *(float4*)(xlds + wave * 2048 + (ct4 * 4 + g) * 256 + lane * 4) = xv;
    }
  }

  int ck = 0;
  const unsigned short* bufp = smem;
  issue_chunk(wsW, b1eff, smem, 0, tid);
  __syncthreads();                              // chunk0 + b1eff[31] + biases + x resident
  issue_chunk(wsW, b1eff, smem, 1, tid);

  bf16x8 hhA[16], hhB[16];

#pragma unroll 1
  for (int t = 31; t >= 0; --t) {
    // ---- chunk c0: L1 = P + b1eff + x@W1x -> h1 (hhA) ----
    {
      bf16x8 xf[4];
      {
        float vv[16];
#pragma unroll
        for (int ct4 = 0; ct4 < 2; ++ct4) {
#pragma unroll
          for (int g = 0; g < 4; ++g) {
            float4 xv = *(const float4*)(xlds + wave * 2048 + (ct4 * 4 + g) * 256 + lane * 4);
            vv[4 * g + 0] = xv.x; vv[4 * g + 1] = xv.y; vv[4 * g + 2] = xv.z; vv[4 * g + 3] = xv.w;
          }
          if (ct4 == 0) { FRAGBUILD(vv, xf[0], xf[1]); } else { FRAGBUILD(vv, xf[2], xf[3]); }
        }
      }
#pragma unroll
      for (int p = 0; p < 4; ++p) {
        const uint4* Pa = (const uint4*)(Pglob + ((size_t)(4 * p + kh) * 65536 + (size_t)row) * 16);
        const uint4* Pb = (const uint4*)(Pglob + ((size_t)(4 * p + 2 + kh) * 65536 + (size_t)row) * 16);
        uint4 pa0 = Pa[0], pa1 = Pa[1];
        uint4 pb0 = Pb[0], pb1 = Pb[1];
        f32x16 a0, a1;
        PDEC(a0, pa0, pa1, 2 * p);
        PDEC(a1, pb0, pb1, 2 * p + 1);
        __builtin_amdgcn_s_setprio(1);
#pragma unroll
        for (int kt = 0; kt < 4; ++kt) {
          bf16x8 w0 = *(const bf16x8*)(bufp + (p * 8 + kt) * 512 + lane8);
          a0 = MF32(w0, xf[kt], a0);
        }
        __builtin_amdgcn_s_setprio(0);
        ACTF0(a0, hhA[4 * p],     hhA[4 * p + 1]);
        __builtin_amdgcn_s_setprio(1);
#pragma unroll
        for (int kt = 0; kt < 4; ++kt) {
          bf16x8 w1 = *(const bf16x8*)(bufp + (p * 8 + 4 + kt) * 512 + lane8);
          a1 = MF32(w1, xf[kt], a1);
        }
        __builtin_amdgcn_s_setprio(0);
        ACTF0(a1, hhA[4 * p + 2], hhA[4 * p + 3]);
      }
    }
    NEXTCHUNK();

    // ---- chunks c1-c4: L2 (hhA -> hhB); ACTF(a0) overlaps a1's MFMA chain ----
#pragma unroll
    for (int p = 0; p < 4; ++p) {
      f32x16 a0, a1; ZER16(a0); ZER16(a1);
      __builtin_amdgcn_s_setprio(1);
#pragma unroll
      for (int kt = 0; kt < 16; ++kt) {
        bf16x8 w0 = *(const bf16x8*)(bufp + kt * 512 + lane8);
        a0 = MF32(w0, hhA[kt], a0);
      }
      __builtin_amdgcn_s_setprio(0);
      ACTF(a0, 256, 2 * p, hhB[4 * p], hhB[4 * p + 1]);      // VALU ∥ next MFMA chain
      __builtin_amdgcn_s_setprio(1);
#pragma unroll
      for (int kt = 0; kt < 16; ++kt) {
        bf16x8 w1 = *(const bf16x8*)(bufp + (16 + kt) * 512 + lane8);
        a1 = MF32(w1, hhA[kt], a1);
      }
      __builtin_amdgcn_s_setprio(0);
      ACTF(a1, 256, 2 * p + 1, hhB[4 * p + 2], hhB[4 * p + 3]);
      NEXTCHUNK();
    }

    // ---- chunks c5-c8: L3 (hhB -> hhA) ----
#pragma unroll
    for (int p = 0; p < 4; ++p) {
      f32x16 a0, a1; ZER16(a0); ZER16(a1);
      __builtin_amdgcn_s_setprio(1);
#pragma unroll
      for (int kt = 0; kt < 16; ++kt) {
        bf16x8 w0 = *(const bf16x8*)(bufp + kt * 512 + lane8);
        a0 = MF32(w0, hhB[kt], a0);
      }
      __builtin_amdgcn_s_setprio(0);
      ACTF(a0, 512, 2 * p, hhA[4 * p], hhA[4 * p + 1]);
      __builtin_amdgcn_s_setprio(1);
#pragma unroll
      for (int kt = 0; kt < 16; ++kt) {
        bf16x8 w1 = *(const bf16x8*)(bufp + (16 + kt) * 512 + lane8);
        a1 = MF32(w1, hhB[kt], a1);
      }
      __builtin_amdgcn_s_setprio(0);
      ACTF(a1, 512, 2 * p + 1, hhA[4 * p + 2], hhA[4 * p + 3]);
      NEXTCHUNK();
    }

    // ---- chunk c9: L4 (hhA -> eps) + epilogue; noise hoisted to overlap MFMA chains ----
    {
      float s1d = C.s1d[t], sqa = C.sqa[t], sqb = C.sqb[t], inva = C.inva[t];
      unsigned kk0 = C.k0[31 - t], kk1 = C.k1[31 - t];

// noise block for one ct4 half (x- and eps-independent; order-free, bit-identical values)
#define ZGEN(ZV, CT4) do { \
  _Pragma("unroll") for (int g = 0; g < 4; ++g) \
    _Pragma("unroll") for (int j = 0; j < 4; ++j) { \
      int n = 32 * (CT4) + 8 * g + 4 * kh + j; \
      (ZV)[4 * g + j] = noise_normal(kk0, kk1, (unsigned)(row * 64 + n)); \
    } \
} while (0)

// epilogue for one ct4 half using precomputed noise
#define EPIZ(CT4, EV, ZV) do { \
  const float* bp4 = biasF + 768 + (CT4) * 32 + kh * 16; \
  _Pragma("unroll") for (int g = 0; g < 4; ++g) { \
    float4 bb = *(const float4*)(bp4 + 4 * g); \
    float* xq = xlds + wave * 2048 + ((CT4) * 4 + g) * 256 + lane * 4; \
    float4 xv = *(const float4*)xq; \
    float xa[4] = {xv.x, xv.y, xv.z, xv.w}; \
    float ba[4] = {bb.x, bb.y, bb.z, bb.w}; \
    _Pragma("unroll") for (int j = 0; j < 4; ++j) { \
      int r = 4 * g + j; \
      float eps = EV[r] + ba[j]; \
      float x0p = fmaf(-s1d, eps, xa[j]) * inva; \
      if (t > 0) { \
        xa[j] = fmaf(sqa, x0p, sqb * (ZV)[r]); \
      } else { \
        xa[j] = x0p; \
      } \
    } \
    if (t > 0) { \
      float4 xs; xs.x = xa[0]; xs.y = xa[1]; xs.z = xa[2]; xs.w = xa[3]; \
      *(float4*)xq = xs; \
    } else { \
      float4 ov; ov.x = xa[0]; ov.y = xa[1]; ov.z = xa[2]; ov.w = xa[3]; \
      *(float4*)(out + (size_t)row * 64 + 32 * (CT4) + 8 * g + 4 * kh) = ov; \
    } \
  } \
} while (0)

      float z0[16], z1[16];
      if (t > 0) ZGEN(z0, 0);                    // fills post-barrier LDS-latency window

      f32x16 e0, e1; ZER16(e0); ZER16(e1);
      __builtin_amdgcn_s_setprio(1);
#pragma unroll
      for (int kt = 0; kt < 16; ++kt) {
        bf16x8 w0 = *(const bf16x8*)(bufp + kt * 512 + lane8);
        e0 = MF32(w0, hhA[kt], e0);
      }
      __builtin_amdgcn_s_setprio(0);
      if (t > 0) ZGEN(z1, 1);                    // VALU ∥ e1's MFMA chain (below)
      EPIZ(0, e0, z0);
      __builtin_amdgcn_s_setprio(1);
#pragma unroll
      for (int kt = 0; kt < 16; ++kt) {
        bf16x8 w1 = *(const bf16x8*)(bufp + (16 + kt) * 512 + lane8);
        e1 = MF32(w1, hhA[kt], e1);
      }
      __builtin_amdgcn_s_setprio(0);
      EPIZ(1, e1, z1);                           // tail is now epilogue-only
#undef ZGEN
#undef EPIZ
      NEXTCHUNK();
    }
  }
}

// ---------- host ----------
static void host_threefry(unsigned k0, unsigned k1, unsigned x0, unsigned x1,
                          unsigned* o0, unsigned* o1) {
  unsigned ks2 = k0 ^ k1 ^ 0x1BD11BDAu;
  x0 += k0; x1 += k1;
#define HR(r) { x0 += x1; x1 = (x1 << r) | (x1 >> (32 - r)); x1 ^= x0; }
  HR(13) HR(15) HR(26) HR(6)
  x0 += k1;  x1 += ks2 + 1u;
  HR(17) HR(29) HR(16) HR(24)
  x0 += ks2; x1 += k0 + 2u;
  HR(13) HR(15) HR(26) HR(6)
  x0 += k0;  x1 += k1 + 3u;
  HR(17) HR(29) HR(16) HR(24)
  x0 += k1;  x1 += ks2 + 4u;
  HR(13) HR(15) HR(26) HR(6)
  x0 += ks2; x1 += k0 + 5u;
#undef HR
  *o0 = x0; *o1 = x1;
}

extern "C" void kernel_launch(void* const* d_in, const int* in_sizes, int n_in,
                              void* d_out, int out_size, void* d_ws, size_t ws_size,
                              hipStream_t stream) {
  const float* cond   = (const float*)d_in[0];
  const float* x_init = (const float*)d_in[1];
  const float* W1 = (const float*)d_in[2];
  const float* b1 = (const float*)d_in[3];
  const float* W2 = (const float*)d_in[4];
  const float* b2 = (const float*)d_in[5];
  const float* W3 = (const float*)d_in[6];
  const float* b3 = (const float*)d_in[7];
  const float* W4 = (const float*)d_in[8];
  const float* b4 = (const float*)d_in[9];

  unsigned short* wbuf = (unsigned short*)d_ws;            // 480 KB frag-major weights
  float* b1eff = (float*)((char*)d_ws + 491520);           // 32 KB, swizzled
  unsigned short* Pbuf = (unsigned short*)((char*)d_ws + 524288);  // 32 MB bf16

  pack_w_k<<<960, 256, 0, stream>>>(W1, W2, W3, W4, wbuf);
  b1eff_k<<<32, 256, 0, stream>>>(W1, b1, b1eff);
  pcond_k<<<512, 256, 0, stream>>>(cond, wbuf, Pbuf);

  Consts C;
  // jax.random.split(jax.random.key(42), 32), threefry_partitionable (verified r2)
  for (int i = 0; i < 32; ++i) {
    unsigned o0, o1;
    host_threefry(0u, 42u, 0u, (unsigned)i, &o0, &o1);
    C.k0[i] = o0; C.k1[i] = o1;
  }
  // schedule constants — identical f32 op sequence to the (passing) r3 device code
  {
    const float bstep = (0.01f - 0.0001f) / 31.0f;
    float abar = 1.0f;
    for (int t = 0; t < 32; ++t) {
      float beta_t = 0.0001f + bstep * (float)t;
      float alpha_t = 1.0f - beta_t;
      abar *= (1.0f - (0.0001f + bstep * (float)t));
      C.s1d[t]  = sqrtf(1.0f - abar);
      C.sqa[t]  = sqrtf(alpha_t);
      C.sqb[t]  = sqrtf(beta_t);
      C.inva[t] = 1.0f / sqrtf(abar);
    }
  }

  const int shmem = 134400;   // 2x32KB weight dbuf + 64KB x + 3.3KB biases
  hipFuncSetAttribute((const void*)diff_main, hipFuncAttributeMaxDynamicSharedMemorySize, 160 * 1024);
  diff_main<<<NBLK, 512, shmem, stream>>>(x_init, b2, b3, b4,
                                          wbuf, b1eff, Pbuf, (float*)d_out, C);
}

// Round 17
// 1269.750 us; speedup vs baseline: 1.0992x; 1.0992x over previous
//
#include <hip/hip_runtime.h>
#include <stdint.h>
#include <stddef.h>

#define NROWS 65536
#define BM 256
#define NBLK (NROWS / BM)   // 256 blocks x 512 threads, 1 block/CU

typedef __attribute__((ext_vector_type(8))) short bf16x8;
typedef __attribute__((ext_vector_type(16))) float f32x16;

// per-step constants, host-precomputed with the exact f32 op sequence of the reference
struct Consts {
  unsigned k0[32]; unsigned k1[32];
  float s1d[32];    // sqrt(1 - alpha_bar[t])
  float sqa[32];    // sqrt(alpha[t])
  float sqb[32];    // sqrt(beta[t])
  float inva[32];   // 1 / sqrt(alpha_bar[t])
};

// ---------- helpers ----------
__device__ __forceinline__ unsigned short f2bf(float f) {
  unsigned u = __float_as_uint(f);
  u += 0x7fffu + ((u >> 16) & 1u);          // RNE to bf16
  return (unsigned short)(u >> 16);
}

__device__ __forceinline__ unsigned cvtpk(float lo, float hi) {
  unsigned r;
  asm("v_cvt_pk_bf16_f32 %0, %1, %2" : "=v"(r) : "v"(lo), "v"(hi));
  return r;
}

__device__ __forceinline__ float silu(float v) {
  return v * __builtin_amdgcn_rcpf(1.0f + __expf(-v));
}

__device__ __forceinline__ void gload_lds16(const void* g, void* l) {
  __builtin_amdgcn_global_load_lds(
      (const __attribute__((address_space(1))) unsigned int*)g,
      (__attribute__((address_space(3))) unsigned int*)l, 16, 0, 0);
}

// Exact JAX noise, threefry_partitionable (verified round 2).
__device__ __forceinline__ float noise_normal(unsigned k0, unsigned k1, unsigned idx) {
  unsigned x0 = 0u, x1 = idx;
  unsigned ks2 = k0 ^ k1 ^ 0x1BD11BDAu;
  x0 += k0; x1 += k1;
#define TFR(r) { x0 += x1; x1 = (x1 << r) | (x1 >> (32 - r)); x1 ^= x0; }
  TFR(13) TFR(15) TFR(26) TFR(6)
  x0 += k1;  x1 += ks2 + 1u;
  TFR(17) TFR(29) TFR(16) TFR(24)
  x0 += ks2; x1 += k0 + 2u;
  TFR(13) TFR(15) TFR(26) TFR(6)
  x0 += k0;  x1 += k1 + 3u;
  TFR(17) TFR(29) TFR(16) TFR(24)
  x0 += k1;  x1 += ks2 + 4u;
  TFR(13) TFR(15) TFR(26) TFR(6)
  x0 += ks2; x1 += k0 + 5u;
#undef TFR
  unsigned bits = x0 ^ x1;
  float f = __uint_as_float((bits >> 9) | 0x3f800000u) - 1.0f;
  const float mn = -0.99999994f;
  float u = f * 2.0f + mn;
  u = fmaxf(mn, u);
  float w = -__logf(fmaf(-u, u, 1.0f));     // == -log1p(-u*u) to ~1e-6 rel
  float p;
  if (w < 5.0f) {
    w -= 2.5f;
    p = 2.81022636e-08f;
    p = fmaf(p, w, 3.43273939e-07f);
    p = fmaf(p, w, -3.5233877e-06f);
    p = fmaf(p, w, -4.39150654e-06f);
    p = fmaf(p, w, 0.00021858087f);
    p = fmaf(p, w, -0.00125372503f);
    p = fmaf(p, w, -0.00417768164f);
    p = fmaf(p, w, 0.246640727f);
    p = fmaf(p, w, 1.50140941f);
  } else {
    w = sqrtf(w) - 3.0f;
    p = -0.000200214257f;
    p = fmaf(p, w, 0.000100950558f);
    p = fmaf(p, w, 0.00134934322f);
    p = fmaf(p, w, -0.00367342844f);
    p = fmaf(p, w, 0.00573950773f);
    p = fmaf(p, w, -0.0076224613f);
    p = fmaf(p, w, 0.00943887047f);
    p = fmaf(p, w, 1.00167406f);
    p = fmaf(p, w, 2.83297682f);
  }
  return 1.41421356f * (p * u);
}

// ---------- init kernels ----------
// wbuf: 480 frags x 1 KB (32x32x16 A-frags, bf16).
//   [0,32):    w1x  [p(4)][ctl(2)][kt(4)]   W1 rows 0..63
//   [32,160):  W2   [cp(4)][ctl(2)][kt(16)]
//   [160,288): W3   [cp(4)][ctl(2)][kt(16)]
//   [288,320): W4   [ctl(2)][kt(16)]
//   [320,480): w1c  [cp(4)][ctl(2)][kt(16)] W1 rows 96..351 (used only by pcond_k)
// frag elem (lane l, e): A[n = 32ct + (l&31)][k = 16kt + (l>>5)*8 + e] = W[k][n]
__global__ void pack_w_k(const float* __restrict__ W1, const float* __restrict__ W2,
                         const float* __restrict__ W3, const float* __restrict__ W4,
                         unsigned short* __restrict__ wbuf) {
  int o = blockIdx.x * 256 + threadIdx.x;     // 960 blocks -> 245760 ushorts
  int f = o >> 9, q = o & 511, l = q >> 3, e = q & 7;
  int l31 = l & 31, kex = (l >> 5) * 8 + e;
  float v;
  if (f < 32) {
    int p = f >> 3, ctl = (f >> 2) & 1, kt = f & 3;
    v = W1[(16 * kt + kex) * 256 + 32 * (2 * p + ctl) + l31];
  } else if (f < 160) {
    int g = f - 32; int cp = g >> 5, ctl = (g >> 4) & 1, kt = g & 15;
    v = W2[(16 * kt + kex) * 256 + 32 * (2 * cp + ctl) + l31];
  } else if (f < 288) {
    int g = f - 160; int cp = g >> 5, ctl = (g >> 4) & 1, kt = g & 15;
    v = W3[(16 * kt + kex) * 256 + 32 * (2 * cp + ctl) + l31];
  } else if (f < 320) {
    int g = f - 288; int ctl = g >> 4, kt = g & 15;
    v = W4[(16 * kt + kex) * 64 + 32 * ctl + l31];
  } else {
    int g = f - 320; int cp = g >> 5, ctl = (g >> 4) & 1, kt = g & 15;
    v = W1[(96 + 16 * kt + kex) * 256 + 32 * (2 * cp + ctl) + l31];
  }
  wbuf[o] = f2bf(v);
}

// b1eff[t][n] = b1[n] + sum_j temb(t)[j] * W1[64+j][n], stored SWIZZLED to D-reg order:
// pos = ct*32 + kh*16 + r, where n = 32ct + (r&3) + 8*(r>>2) + 4*kh
__global__ void b1eff_k(const float* __restrict__ W1, const float* __restrict__ b1,
                        float* __restrict__ b1eff) {
  int t = blockIdx.x, n = threadIdx.x;
  float acc = b1[n];
#pragma unroll
  for (int j = 0; j < 16; ++j) {
    float arg = (float)t * expf((float)j * (6.907755278982137f / 15.0f));
    acc += sinf(arg) * W1[(64 + j) * 256 + n] + cosf(arg) * W1[(80 + j) * 256 + n];
  }
  int sw = ((n >> 5) << 5) + (((n >> 2) & 1) << 4) + (n & 3) + (((n >> 3) & 3) << 2);
  b1eff[t * 256 + sw] = acc;
}

#define MF32(W, B, C) __builtin_amdgcn_mfma_f32_32x32x16_bf16((W), (B), (C), 0, 0, 0)

// ---------- P = cond @ W1c, once, stored bf16 in D-reg order ----------
// layout: P[slot = 2*ct + kh][row][16 bf16]
__global__ __launch_bounds__(256) void pcond_k(const float* __restrict__ cond,
                                               const unsigned short* __restrict__ wbuf,
                                               unsigned short* __restrict__ P) {
  const int tid = threadIdx.x;
  const int wave = tid >> 6, lane = tid & 63;
  const int l31 = lane & 31, kh = lane >> 5;
  const int row = blockIdx.x * 128 + wave * 32 + l31;

  bf16x8 cf[16];
#pragma unroll
  for (int kt = 0; kt < 16; ++kt) {
    const float* p = cond + (size_t)row * 256 + 16 * kt + 8 * kh;
    float4 a = *(const float4*)p;
    float4 b = *(const float4*)(p + 4);
    union { bf16x8 f; unsigned u[4]; } cu;
    cu.u[0] = cvtpk(a.x, a.y); cu.u[1] = cvtpk(a.z, a.w);
    cu.u[2] = cvtpk(b.x, b.y); cu.u[3] = cvtpk(b.z, b.w);
    cf[kt] = cu.f;
  }

#define PSTORE(AV, CT) do { \
  uint4 u0_, u1_; \
  u0_.x = cvtpk(AV[0], AV[1]);   u0_.y = cvtpk(AV[2], AV[3]); \
  u0_.z = cvtpk(AV[4], AV[5]);   u0_.w = cvtpk(AV[6], AV[7]); \
  u1_.x = cvtpk(AV[8], AV[9]);   u1_.y = cvtpk(AV[10], AV[11]); \
  u1_.z = cvtpk(AV[12], AV[13]); u1_.w = cvtpk(AV[14], AV[15]); \
  uint4* pp_ = (uint4*)(P + ((size_t)((CT) * 2 + kh) * 65536 + (size_t)row) * 16); \
  pp_[0] = u0_; pp_[1] = u1_; \
} while (0)

#pragma unroll
  for (int cp = 0; cp < 4; ++cp) {
    f32x16 a0, a1;
#pragma unroll
    for (int z = 0; z < 16; ++z) { a0[z] = 0.0f; a1[z] = 0.0f; }
#pragma unroll
    for (int kt = 0; kt < 16; ++kt) {
      bf16x8 w0 = *(const bf16x8*)(wbuf + (size_t)(320 + cp * 32 + kt) * 512 + lane * 8);
      bf16x8 w1 = *(const bf16x8*)(wbuf + (size_t)(320 + cp * 32 + 16 + kt) * 512 + lane * 8);
      a0 = MF32(w0, cf[kt], a0);
      a1 = MF32(w1, cf[kt], a1);
    }
    PSTORE(a0, 2 * cp);
    PSTORE(a1, 2 * cp + 1);
  }
#undef PSTORE
}

// ---------- weight-chunk staging: 10 chunks/step x 32 KB, double-buffered ----------
// LDS bytes: [0,65536) weight dbuf (2x32KB) | [65536,131072) xlds | [131072,134400) biasF
__device__ __forceinline__ void issue_chunk(const unsigned short* __restrict__ wsW,
                                            const float* __restrict__ b1eff,
                                            unsigned short* smem, int k, int tid) {
  if (k >= 320) return;
  int c = k % 10;
  unsigned short* dst = smem + (k & 1) * 16384;
  const unsigned short* src = wsW + c * 16384;
#pragma unroll
  for (int i = 0; i < 4; ++i) {
    int off = (i * 512 + tid) * 8;
    gload_lds16(src + off, dst + off);
  }
  if (c == 9 && tid < 64) {                    // prefetch next step's b1eff
    int tn = 30 - k / 10;
    if (tn >= 0) gload_lds16(b1eff + tn * 256 + tid * 4, (float*)(smem + 65536) + tid * 4);
  }
}

// build 2 B-frags (32 cols -> k-tiles 2ct,2ct+1) from 16 f32 in D-reg order (r6-verified)
#define FRAGBUILD(vv, D0, D1) do { \
  unsigned c0_ = cvtpk(vv[0], vv[1]),  c2_ = cvtpk(vv[2], vv[3]); \
  unsigned c1_ = cvtpk(vv[4], vv[5]),  c3_ = cvtpk(vv[6], vv[7]); \
  asm volatile("v_permlane32_swap_b32 %0, %1" : "+v"(c0_), "+v"(c1_)); \
  asm volatile("v_permlane32_swap_b32 %0, %1" : "+v"(c2_), "+v"(c3_)); \
  union { bf16x8 f; unsigned u[4]; } F0_; \
  F0_.u[0] = c0_; F0_.u[1] = c2_; F0_.u[2] = c1_; F0_.u[3] = c3_; (D0) = F0_.f; \
  unsigned d0_ = cvtpk(vv[8], vv[9]),   d2_ = cvtpk(vv[10], vv[11]); \
  unsigned d1_ = cvtpk(vv[12], vv[13]), d3_ = cvtpk(vv[14], vv[15]); \
  asm volatile("v_permlane32_swap_b32 %0, %1" : "+v"(d0_), "+v"(d1_)); \
  asm volatile("v_permlane32_swap_b32 %0, %1" : "+v"(d2_), "+v"(d3_)); \
  union { bf16x8 f; unsigned u[4]; } F1_; \
  F1_.u[0] = d0_; F1_.u[1] = d2_; F1_.u[2] = d1_; F1_.u[3] = d3_; (D1) = F1_.f; \
} while (0)

// bias-add + silu + repack to B-frags
#define ACTF(AV, BOFF, CT, D0, D1) do { \
  const float* bp_ = biasF + (BOFF) + (CT) * 32 + kh * 16; \
  float4 b0_ = *(const float4*)bp_; \
  float4 b1_ = *(const float4*)(bp_ + 4); \
  float4 b2_ = *(const float4*)(bp_ + 8); \
  float4 b3_ = *(const float4*)(bp_ + 12); \
  float vv[16]; \
  vv[0]=AV[0]+b0_.x; vv[1]=AV[1]+b0_.y; vv[2]=AV[2]+b0_.z; vv[3]=AV[3]+b0_.w; \
  vv[4]=AV[4]+b1_.x; vv[5]=AV[5]+b1_.y; vv[6]=AV[6]+b1_.z; vv[7]=AV[7]+b1_.w; \
  vv[8]=AV[8]+b2_.x; vv[9]=AV[9]+b2_.y; vv[10]=AV[10]+b2_.z; vv[11]=AV[11]+b2_.w; \
  vv[12]=AV[12]+b3_.x; vv[13]=AV[13]+b3_.y; vv[14]=AV[14]+b3_.z; vv[15]=AV[15]+b3_.w; \
  _Pragma("unroll") for (int r_ = 0; r_ < 16; ++r_) vv[r_] = silu(vv[r_]); \
  FRAGBUILD(vv, D0, D1); \
} while (0)

// silu-only (bias already in acc) + repack
#define ACTF0(AV, D0, D1) do { \
  float vv[16]; \
  _Pragma("unroll") for (int r_ = 0; r_ < 16; ++r_) vv[r_] = silu(AV[r_]); \
  FRAGBUILD(vv, D0, D1); \
} while (0)

// acc init = P(bf16, D-order) + b1eff_t (LDS, D-order)
#define PDEC(ACC, PA, PB, CT) do { \
  const float* bb_ = biasF + (CT) * 32 + kh * 16; \
  float4 b0_ = *(const float4*)bb_; \
  float4 b1_ = *(const float4*)(bb_ + 4); \
  float4 b2_ = *(const float4*)(bb_ + 8); \
  float4 b3_ = *(const float4*)(bb_ + 12); \
  float ba_[16] = {b0_.x,b0_.y,b0_.z,b0_.w, b1_.x,b1_.y,b1_.z,b1_.w, \
                   b2_.x,b2_.y,b2_.z,b2_.w, b3_.x,b3_.y,b3_.z,b3_.w}; \
  unsigned uu_[8] = {PA.x, PA.y, PA.z, PA.w, PB.x, PB.y, PB.z, PB.w}; \
  _Pragma("unroll") for (int w_ = 0; w_ < 8; ++w_) { \
    ACC[2 * w_]     = __uint_as_float(uu_[w_] << 16)          + ba_[2 * w_]; \
    ACC[2 * w_ + 1] = __uint_as_float(uu_[w_] & 0xffff0000u)  + ba_[2 * w_ + 1]; } \
} while (0)

#define NEXTCHUNK() do { __syncthreads(); ++ck; \
  bufp = smem + (ck & 1) * 16384; \
  issue_chunk(wsW, b1eff, smem, ck + 1, tid); } while (0)

#define ZER16(A) { _Pragma("unroll") for (int z_ = 0; z_ < 16; ++z_) (A)[z_] = 0.0f; }

// ---------- main persistent kernel ----------
__global__ __launch_bounds__(512, 1) void diff_main(
    const float* __restrict__ x_init,
    const float* __restrict__ b2g, const float* __restrict__ b3g, const float* __restrict__ b4g,
    const unsigned short* __restrict__ wsW, const float* __restrict__ b1eff,
    const unsigned short* __restrict__ Pglob,
    float* __restrict__ out, Consts C) {
  extern __shared__ unsigned short smem[];
  float* xlds  = (float*)(smem + 32768);       // byte 65536: 64 KB x-master [wave][q][lane][4]
  float* biasF = (float*)(smem + 65536);       // byte 131072: b1eff_t[256] b2[256] b3[256] b4[64]

  const int tid = threadIdx.x;
  const int wave = tid >> 6, lane = tid & 63;
  const int l31 = lane & 31, kh = lane >> 5;
  const int lane8 = lane * 8;
  const int row = blockIdx.x * BM + wave * 32 + l31;

  // stage b2/b3/b4 -> LDS, swizzled to D-reg order
  for (int i = tid; i < 576; i += 512) {
    float v; int n, base;
    if (i < 256)      { v = b2g[i];       n = i;       base = 256; }
    else if (i < 512) { v = b3g[i - 256]; n = i - 256; base = 512; }
    else              { v = b4g[i - 512]; n = i - 512; base = 768; }
    int sw = ((n >> 5) << 5) + (((n >> 2) & 1) << 4) + (n & 3) + (((n >> 3) & 3) << 2);
    biasF[base + sw] = v;
  }
  // stage b1eff[31]
  if (tid < 64) gload_lds16(b1eff + 31 * 256 + tid * 4, biasF + tid * 4);

  // x master -> LDS (frags rebuilt from LDS at each step's c0)
#pragma unroll
  for (int ct4 = 0; ct4 < 2; ++ct4) {
#pragma unroll
    for (int g = 0; g < 4; ++g) {
      float4 xv = *(const float4*)(x_init + (size_t)row * 64 + 32 * ct4 + 8 * g + 4 * kh);
      *(float4*)(xlds + wave * 2048 + (ct4 * 4 + g) * 256 + lane * 4) = xv;
    }
  }

  int ck = 0;
  const unsigned short* bufp = smem;
  issue_chunk(wsW, b1eff, smem, 0, tid);
  __syncthreads();                              // chunk0 + b1eff[31] + biases + x resident
  issue_chunk(wsW, b1eff, smem, 1, tid);

  bf16x8 hhA[16], hhB[16];

#pragma unroll 1
  for (int t = 31; t >= 0; --t) {
    // ---- chunk c0: L1 = P + b1eff + x@W1x -> h1 (hhA) ----
    {
      bf16x8 xf[4];
      {
        float vv[16];
#pragma unroll
        for (int ct4 = 0; ct4 < 2; ++ct4) {
#pragma unroll
          for (int g = 0; g < 4; ++g) {
            float4 xv = *(const float4*)(xlds + wave * 2048 + (ct4 * 4 + g) * 256 + lane * 4);
            vv[4 * g + 0] = xv.x; vv[4 * g + 1] = xv.y; vv[4 * g + 2] = xv.z; vv[4 * g + 3] = xv.w;
          }
          if (ct4 == 0) { FRAGBUILD(vv, xf[0], xf[1]); } else { FRAGBUILD(vv, xf[2], xf[3]); }
        }
      }
#pragma unroll
      for (int p = 0; p < 4; ++p) {
        const uint4* Pa = (const uint4*)(Pglob + ((size_t)(4 * p + kh) * 65536 + (size_t)row) * 16);
        const uint4* Pb = (const uint4*)(Pglob + ((size_t)(4 * p + 2 + kh) * 65536 + (size_t)row) * 16);
        uint4 pa0 = Pa[0], pa1 = Pa[1];
        uint4 pb0 = Pb[0], pb1 = Pb[1];
        f32x16 a0, a1;
        PDEC(a0, pa0, pa1, 2 * p);
        PDEC(a1, pb0, pb1, 2 * p + 1);
        __builtin_amdgcn_s_setprio(1);
#pragma unroll
        for (int kt = 0; kt < 4; ++kt) {
          bf16x8 w0 = *(const bf16x8*)(bufp + (p * 8 + kt) * 512 + lane8);
          a0 = MF32(w0, xf[kt], a0);
        }
        __builtin_amdgcn_s_setprio(0);
        ACTF0(a0, hhA[4 * p],     hhA[4 * p + 1]);
        __builtin_amdgcn_s_setprio(1);
#pragma unroll
        for (int kt = 0; kt < 4; ++kt) {
          bf16x8 w1 = *(const bf16x8*)(bufp + (p * 8 + 4 + kt) * 512 + lane8);
          a1 = MF32(w1, xf[kt], a1);
        }
        __builtin_amdgcn_s_setprio(0);
        ACTF0(a1, hhA[4 * p + 2], hhA[4 * p + 3]);
      }
    }
    NEXTCHUNK();

    // ---- chunks c1-c4: L2 (hhA -> hhB); ACTF(a0) overlaps a1's MFMA chain ----
#pragma unroll
    for (int p = 0; p < 4; ++p) {
      f32x16 a0, a1; ZER16(a0); ZER16(a1);
      __builtin_amdgcn_s_setprio(1);
#pragma unroll
      for (int kt = 0; kt < 16; ++kt) {
        bf16x8 w0 = *(const bf16x8*)(bufp + kt * 512 + lane8);
        a0 = MF32(w0, hhA[kt], a0);
      }
      __builtin_amdgcn_s_setprio(0);
      ACTF(a0, 256, 2 * p, hhB[4 * p], hhB[4 * p + 1]);      // VALU ∥ next MFMA chain
      __builtin_amdgcn_s_setprio(1);
#pragma unroll
      for (int kt = 0; kt < 16; ++kt) {
        bf16x8 w1 = *(const bf16x8*)(bufp + (16 + kt) * 512 + lane8);
        a1 = MF32(w1, hhA[kt], a1);
      }
      __builtin_amdgcn_s_setprio(0);
      ACTF(a1, 256, 2 * p + 1, hhB[4 * p + 2], hhB[4 * p + 3]);
      NEXTCHUNK();
    }

    // ---- chunks c5-c8: L3 (hhB -> hhA) ----
#pragma unroll
    for (int p = 0; p < 4; ++p) {
      f32x16 a0, a1; ZER16(a0); ZER16(a1);
      __builtin_amdgcn_s_setprio(1);
#pragma unroll
      for (int kt = 0; kt < 16; ++kt) {
        bf16x8 w0 = *(const bf16x8*)(bufp + kt * 512 + lane8);
        a0 = MF32(w0, hhB[kt], a0);
      }
      __builtin_amdgcn_s_setprio(0);
      ACTF(a0, 512, 2 * p, hhA[4 * p], hhA[4 * p + 1]);
      __builtin_amdgcn_s_setprio(1);
#pragma unroll
      for (int kt = 0; kt < 16; ++kt) {
        bf16x8 w1 = *(const bf16x8*)(bufp + (16 + kt) * 512 + lane8);
        a1 = MF32(w1, hhB[kt], a1);
      }
      __builtin_amdgcn_s_setprio(0);
      ACTF(a1, 512, 2 * p + 1, hhA[4 * p + 2], hhA[4 * p + 3]);
      NEXTCHUNK();
    }

    // ---- chunk c9: L4 (hhA -> eps) + epilogue; epilogue(ct4=0) overlaps e1's chain ----
    {
      float s1d = C.s1d[t], sqa = C.sqa[t], sqb = C.sqb[t], inva = C.inva[t];
      unsigned kk0 = C.k0[31 - t], kk1 = C.k1[31 - t];

#define EPI(CT4, EV) do { \
  const float* bp4 = biasF + 768 + (CT4) * 32 + kh * 16; \
  _Pragma("unroll") for (int g = 0; g < 4; ++g) { \
    float4 bb = *(const float4*)(bp4 + 4 * g); \
    float* xq = xlds + wave * 2048 + ((CT4) * 4 + g) * 256 + lane * 4; \
    float4 xv = *(const float4*)xq; \
    float xa[4] = {xv.x, xv.y, xv.z, xv.w}; \
    float ba[4] = {bb.x, bb.y, bb.z, bb.w}; \
    _Pragma("unroll") for (int j = 0; j < 4; ++j) { \
      int r = 4 * g + j; \
      float eps = EV[r] + ba[j]; \
      float x0p = fmaf(-s1d, eps, xa[j]) * inva; \
      if (t > 0) { \
        int n = 32 * (CT4) + 8 * g + 4 * kh + j; \
        float z = noise_normal(kk0, kk1, (unsigned)(row * 64 + n)); \
        xa[j] = fmaf(sqa, x0p, sqb * z); \
      } else { \
        xa[j] = x0p; \
      } \
    } \
    if (t > 0) { \
      float4 xs; xs.x = xa[0]; xs.y = xa[1]; xs.z = xa[2]; xs.w = xa[3]; \
      *(float4*)xq = xs; \
    } else { \
      float4 ov; ov.x = xa[0]; ov.y = xa[1]; ov.z = xa[2]; ov.w = xa[3]; \
      *(float4*)(out + (size_t)row * 64 + 32 * (CT4) + 8 * g + 4 * kh) = ov; \
    } \
  } \
} while (0)

      f32x16 e0, e1; ZER16(e0); ZER16(e1);
      __builtin_amdgcn_s_setprio(1);
#pragma unroll
      for (int kt = 0; kt < 16; ++kt) {
        bf16x8 w0 = *(const bf16x8*)(bufp + kt * 512 + lane8);
        e0 = MF32(w0, hhA[kt], e0);
      }
      __builtin_amdgcn_s_setprio(0);
      EPI(0, e0);                                // noise VALU ∥ e1's MFMA chain
      __builtin_amdgcn_s_setprio(1);
#pragma unroll
      for (int kt = 0; kt < 16; ++kt) {
        bf16x8 w1 = *(const bf16x8*)(bufp + (16 + kt) * 512 + lane8);
        e1 = MF32(w1, hhA[kt], e1);
      }
      __builtin_amdgcn_s_setprio(0);
      EPI(1, e1);
#undef EPI
      NEXTCHUNK();
    }
  }
}

// ---------- host ----------
static void host_threefry(unsigned k0, unsigned k1, unsigned x0, unsigned x1,
                          unsigned* o0, unsigned* o1) {
  unsigned ks2 = k0 ^ k1 ^ 0x1BD11BDAu;
  x0 += k0; x1 += k1;
#define HR(r) { x0 += x1; x1 = (x1 << r) | (x1 >> (32 - r)); x1 ^= x0; }
  HR(13) HR(15) HR(26) HR(6)
  x0 += k1;  x1 += ks2 + 1u;
  HR(17) HR(29) HR(16) HR(24)
  x0 += ks2; x1 += k0 + 2u;
  HR(13) HR(15) HR(26) HR(6)
  x0 += k0;  x1 += k1 + 3u;
  HR(17) HR(29) HR(16) HR(24)
  x0 += k1;  x1 += ks2 + 4u;
  HR(13) HR(15) HR(26) HR(6)
  x0 += ks2; x1 += k0 + 5u;
#undef HR
  *o0 = x0; *o1 = x1;
}

extern "C" void kernel_launch(void* const* d_in, const int* in_sizes, int n_in,
                              void* d_out, int out_size, void* d_ws, size_t ws_size,
                              hipStream_t stream) {
  const float* cond   = (const float*)d_in[0];
  const float* x_init = (const float*)d_in[1];
  const float* W1 = (const float*)d_in[2];
  const float* b1 = (const float*)d_in[3];
  const float* W2 = (const float*)d_in[4];
  const float* b2 = (const float*)d_in[5];
  const float* W3 = (const float*)d_in[6];
  const float* b3 = (const float*)d_in[7];
  const float* W4 = (const float*)d_in[8];
  const float* b4 = (const float*)d_in[9];

  unsigned short* wbuf = (unsigned short*)d_ws;            // 480 KB frag-major weights
  float* b1eff = (float*)((char*)d_ws + 491520);           // 32 KB, swizzled
  unsigned short* Pbuf = (unsigned short*)((char*)d_ws + 524288);  // 32 MB bf16

  pack_w_k<<<960, 256, 0, stream>>>(W1, W2, W3, W4, wbuf);
  b1eff_k<<<32, 256, 0, stream>>>(W1, b1, b1eff);
  pcond_k<<<512, 256, 0, stream>>>(cond, wbuf, Pbuf);

  Consts C;
  // jax.random.split(jax.random.key(42), 32), threefry_partitionable (verified r2)
  for (int i = 0; i < 32; ++i) {
    unsigned o0, o1;
    host_threefry(0u, 42u, 0u, (unsigned)i, &o0, &o1);
    C.k0[i] = o0; C.k1[i] = o1;
  }
  // schedule constants — identical f32 op sequence to the (passing) r3 device code
  {
    const float bstep = (0.01f - 0.0001f) / 31.0f;
    float abar = 1.0f;
    for (int t = 0; t < 32; ++t) {
      float beta_t = 0.0001f + bstep * (float)t;
      float alpha_t = 1.0f - beta_t;
      abar *= (1.0f - (0.0001f + bstep * (float)t));
      C.s1d[t]  = sqrtf(1.0f - abar);
      C.sqa[t]  = sqrtf(alpha_t);
      C.sqb[t]  = sqrtf(beta_t);
      C.inva[t] = 1.0f / sqrtf(abar);
    }
  }

  const int shmem = 134400;   // 2x32KB weight dbuf + 64KB x + 3.3KB biases
  hipFuncSetAttribute((const void*)diff_main, hipFuncAttributeMaxDynamicSharedMemorySize, 160 * 1024);
  diff_main<<<NBLK, 512, shmem, stream>>>(x_init, b2, b3, b4,
                                          wbuf, b1eff, Pbuf, (float*)d_out, C);
}